// Round 5
// baseline (11146.052 us; speedup 1.0000x reference)
//
#include <hip/hip_runtime.h>
#include <hip/hip_bf16.h>

// ---------------------------------------------------------------------------
// TernaryLSTM R19 = R18 minus group-wide barrier: PER-WAVE producer waits.
//   Dependency fact: wave w's rec k-slice [256*(w&3),+256) consumes h from
//   only 8 producer WGs (quarter w&3). Each wave polls just those 8 flags
//   and proceeds; no group rendezvous, no epoch broadcast. Safe with 2
//   h-buffers because gates(t) need all 4 k-slice slabs => every WG's
//   flag(t+1) transitively requires all 32 flags(t) (skew <= 1 step).
//   Flags: one 128B line per (group, quarter) [8 writers, 32 pollers/line,
//   vs R18's 32 writers + 256 pollers on one line]. Waves 0-3 poll IC;
//   waves 4-7 take the quarter epoch via LDS release/acquire.
//   Producer side: gates threads store h directly (st_cc2, coalesces to
//   8 line-transactions), explicit vmcnt(0), sync2, lane0-of-wave4 flag.
//   All cross-WG ops remain sc0 sc1 (device/IC scope — R15/R18-proven).
//   Compute unchanged from R18: Wr in VGPRs (8 waves x 32 bf16x8), Wk in
//   LDS (128KB XOR-swizzled), all-8-wave rec, xproj in hidden window.
// ---------------------------------------------------------------------------

typedef __attribute__((ext_vector_type(8))) __bf16 bf16x8;
typedef __attribute__((ext_vector_type(4))) float f32x4;

#define NWG 256
#define WGT 512
#define T_N 1024

// ---------------- alpha reductions -----------------------------------------
__global__ void absum_kernel(const float* __restrict__ w, int n,
                             double* __restrict__ partial) {
  __shared__ double sd[256];
  double s = 0.0;
  for (int i = blockIdx.x * 256 + threadIdx.x; i < n; i += 256 * 256)
    s += fabs((double)w[i]);
  sd[threadIdx.x] = s;
  __syncthreads();
  for (int k = 128; k > 0; k >>= 1) {
    if (threadIdx.x < k) sd[threadIdx.x] += sd[threadIdx.x + k];
    __syncthreads();
  }
  if (threadIdx.x == 0) partial[blockIdx.x] = sd[0];
}

__global__ void alpha_finalize(const double* __restrict__ pk,
                               const double* __restrict__ pr,
                               float* __restrict__ alphas) {
  __shared__ double sd[256];
  int t = threadIdx.x;
  sd[t] = pk[t];
  __syncthreads();
  for (int s = 128; s > 0; s >>= 1) {
    if (t < s) sd[t] += sd[t + s];
    __syncthreads();
  }
  if (t == 0) alphas[0] = (float)(sd[0] / (512.0 * 4096.0));
  __syncthreads();
  sd[t] = pr[t];
  __syncthreads();
  for (int s = 128; s > 0; s >>= 1) {
    if (t < s) sd[t] += sd[t + s];
    __syncthreads();
  }
  if (t == 0) alphas[1] = (float)(sd[0] / (1024.0 * 4096.0));
}

// ------ quantize + transpose to UNIT-MAJOR cols: wt[u*4+g][k] --------------
__global__ void quant_kernel(const float* __restrict__ w, int kbits,
                             const float* __restrict__ alphas, int ai,
                             __hip_bfloat16* __restrict__ wt, int total) {
  int idx = blockIdx.x * 256 + threadIdx.x;
  if (idx >= total) return;
  float thr = 0.7f * alphas[ai];
  int K = 1 << kbits;
  int c = idx >> kbits;  // unit-major col: unit = c>>2, gate = c&3
  int k = idx & (K - 1);
  float v = w[k * 4096 + (c & 3) * 1024 + (c >> 2)];
  float q = (fabsf(v) < thr) ? 0.0f : ((v > 0.0f) ? 1.0f : ((v < 0.0f) ? -1.0f : 0.0f));
  wt[idx] = __float2bfloat16(q);  // exact {-1,0,+1}
}

// ---------------- helpers ---------------------------------------------------
__device__ __forceinline__ bf16x8 cvt2(f32x4 a, f32x4 b) {
  bf16x8 r;
  r[0] = (__bf16)a[0]; r[1] = (__bf16)a[1];
  r[2] = (__bf16)a[2]; r[3] = (__bf16)a[3];
  r[4] = (__bf16)b[0]; r[5] = (__bf16)b[1];
  r[6] = (__bf16)b[2]; r[7] = (__bf16)b[3];
  return r;
}
// Device-scope (IC) ops — R12/R15/R18-proven protocol.
__device__ __forceinline__ void ld16cc(bf16x8* d, const __hip_bfloat16* p) {
  asm volatile("global_load_dwordx4 %0, %1, off sc0 sc1"
               : "=v"(*d) : "v"(p) : "memory");
}
__device__ __forceinline__ void st_cc2(__hip_bfloat16* p, unsigned bits) {
  asm volatile("global_store_short %0, %1, off sc0 sc1" ::"v"(p), "v"(bits)
               : "memory");
}
__device__ __forceinline__ void stflag(int* p, int v) {
  asm volatile("global_store_dword %0, %1, off sc0 sc1" ::"v"(p), "v"(v)
               : "memory");
}
__device__ __forceinline__ int ldflag(const int* p) {
  int v;
  asm volatile("global_load_dword %0, %1, off sc0 sc1\n\ts_waitcnt vmcnt(0)"
               : "=v"(v) : "v"(p) : "memory");
  return v;
}
__device__ __forceinline__ unsigned bf16b(float f) {
  return (unsigned)__builtin_bit_cast(unsigned short, __float2bfloat16(f));
}
__device__ __forceinline__ float sigm(float z) { return 1.0f / (1.0f + __expf(-z)); }
__device__ __forceinline__ float tanhx(float z) {
  float e = __expf(-2.0f * fabsf(z));
  return __builtin_copysignf((1.0f - e) / (1.0f + e), z);
}

// ---------------- persistent LSTM kernel -----------------------------------
// flags layout: flags[(g*4 + quarter)*32 + slot], slot = u&7 (one 128B line
// per (group, quarter); 8 writers, 32 pollers per line).
__global__ void __launch_bounds__(WGT, 2)
lstm_persist(const float* __restrict__ bias4, const float* __restrict__ alphas,
             const float* __restrict__ x,             // [B][T][I] f32
             const __hip_bfloat16* __restrict__ wtk,  // [4096][512]  unit-major
             const __hip_bfloat16* __restrict__ wtr,  // [4096][1024] unit-major
             __hip_bfloat16* __restrict__ hbuf,       // [2][8][8][1024] bf16
             float* __restrict__ out,                 // [B][T][U] f32
             int* __restrict__ flags) {
  extern __shared__ char lds[];
  char* lwtk = lds;                     // 128 cols x 1024B swizzled = 131072
  float* lz = (float*)(lds + 131072);   // 4 slabs x [8][132] f32 = 16896
  float* lxz = (float*)(lds + 147968);  // 2 bufs  x [8][132] f32 = 8448
  int* lmeta = (int*)(lds + 156416);    // [0..3] per-quarter epoch

  const int tid = threadIdx.x;
  const int wg = blockIdx.x;
  const int lane = tid & 63;
  const int wave = tid >> 6;
  const int r16 = lane & 15;
  const int kb8 = (lane >> 4) << 3;  // k-chunk 0,8,16,24

  const int g = wg >> 5;   // software group 0..7 (8 batch rows each)
  const int u = wg & 31;   // unit-block 0..31: units [32u, 32u+32)
  const int rb0 = g << 3;  // group's first batch row

  if (tid < 4) lmeta[tid] = 0;

  // my flag slot (written by wave4 lane0): line (g,quarter u>>3), slot u&7
  int* myflag = flags + ((g << 2) + (u >> 3)) * 32 + (u & 7);
  // poll line for wave<4: quarter = wave
  const int* pollp = flags + ((g << 2) + (wave & 3)) * 32 + (lane & 7);

  // ---- stage Wk slice into LDS: local cols [0,128) = global [128u,+128) ---
  for (int it = tid; it < 8192; it += WGT) {
    int c = it >> 6, kk = (it & 63) << 3;
    bf16x8 v = *(const bf16x8*)(wtk + (size_t)(u * 128 + c) * 512 + kk);
    *(bf16x8*)(lwtk + (c << 10) + ((kk << 1) ^ ((c & 7) << 4))) = v;
  }

  // ---- Wr slice into VGPRs: wave w -> k-slice [(w&3)*256,+256),
  //      col half (w>>2)*64: 8 ksteps x 4 ntiles of bf16x8 frags ----
  const int ks0 = (wave & 3) << 8;
  bf16x8 bw[8][4];
  {
    const __hip_bfloat16* wb =
        wtr + (size_t)(u * 128 + ((wave >> 2) << 6) + r16) * 1024 + ks0 + kb8;
#pragma unroll
    for (int ks = 0; ks < 8; ++ks)
#pragma unroll
      for (int nt = 0; nt < 4; ++nt)
        bw[ks][nt] = *(const bf16x8*)(wb + (size_t)nt * 16 * 1024 + (ks << 5));
  }

  const float ak = alphas[0];
  const float ar = alphas[1];

  // gates mapping (threads 0..255): 1 cell = (row rl 0..7, unit-local ul 0..31)
  const int rl = tid >> 5;
  const int ul = tid & 31;
  float bias_c[4];
#pragma unroll
  for (int gg = 0; gg < 4; ++gg)
    bias_c[gg] = bias4[gg * 1024 + u * 32 + ul];
  float cst = 0.0f;
  __hip_bfloat16* hst = hbuf + (g << 13) + (rl << 10) + u * 32 + ul;
  float* outp = out + ((size_t)(rb0 + rl) << 20) + u * 32 + ul;

  // x-projection of step tt into lxz[par]: wave w does n-tile w (16 cols).
  auto xproj = [&](int tt, int par) {
    const float* xr =
        x + ((size_t)(rb0 + (r16 & 7)) << 19) + ((size_t)tt << 9) + kb8;
    const int cloc = (wave << 4) + r16;
    const char* bbase = lwtk + (cloc << 10);
    const int bxor = (cloc & 7) << 4;
    f32x4 a = {0.f, 0.f, 0.f, 0.f};
#pragma unroll
    for (int kw = 0; kw < 16; ++kw) {
      bf16x8 af = cvt2(*(const f32x4*)(xr + kw * 32),
                       *(const f32x4*)(xr + kw * 32 + 4));
      bf16x8 bf = *(const bf16x8*)(bbase + ((((kw << 5) + kb8) << 1) ^ bxor));
      a = __builtin_amdgcn_mfma_f32_16x16x32_bf16(af, bf, a, 0, 0, 0);
    }
    if (lane < 32) {
      float* dst = lxz + par * 1056 + (wave << 4) + (lane & 15);
#pragma unroll
      for (int j = 0; j < 4; ++j)
        dst[(((lane >> 4) << 2) + j) * 132] = a[j];
    }
  };

  __syncthreads();  // staging + lmeta visible
  xproj(0, 0);      // prologue: t=0 x-projection into lxz[0]

  // ---- main loop ----
  for (int t = 0; t < T_N; ++t) {
    // ---- rec: all 8 waves, per-wave producer wait + k-slice MFMA ----
    {
      f32x4 acc[4];
#pragma unroll
      for (int nt = 0; nt < 4; ++nt) acc[nt] = (f32x4){0.f, 0.f, 0.f, 0.f};
      if (t > 0) {
        // per-wave wait: quarter (w&3) needs its 8 producers at >= t.
        if (wave < 4) {
          for (;;) {
            int v = (lane < 8) ? ldflag(pollp) : 0x7fffffff;
            if (__all(v >= t)) break;
          }
          if (lane == 0)
            __hip_atomic_store(&lmeta[wave], t, __ATOMIC_RELEASE,
                               __HIP_MEMORY_SCOPE_WORKGROUP);
        } else {
          while (__hip_atomic_load(&lmeta[wave - 4], __ATOMIC_ACQUIRE,
                                   __HIP_MEMORY_SCOPE_WORKGROUP) < t) {}
        }
        bf16x8 fr[8];
        if (r16 < 8) {  // A rows 8..15 are zero padding
          const __hip_bfloat16* hrow =
              hbuf + ((t & 1) << 16) + (g << 13) + (r16 << 10) + ks0 + kb8;
#pragma unroll
          for (int ks = 0; ks < 8; ++ks) ld16cc(&fr[ks], hrow + (ks << 5));
        } else {
#pragma unroll
          for (int ks = 0; ks < 8; ++ks)
#pragma unroll
            for (int j = 0; j < 8; ++j) fr[ks][j] = (__bf16)0.0f;
        }
        asm volatile("s_waitcnt vmcnt(0)" ::: "memory");
        __builtin_amdgcn_sched_barrier(0);
#pragma unroll
        for (int ks = 0; ks < 8; ++ks)
#pragma unroll
          for (int nt = 0; nt < 4; ++nt)
            acc[nt] = __builtin_amdgcn_mfma_f32_16x16x32_bf16(
                fr[ks], bw[ks][nt], acc[nt], 0, 0, 0);
      }
      if (lane < 32) {  // store C rows 0..7 only
        float* dst = lz + (wave & 3) * 1056 + ((wave >> 2) << 6) + (lane & 15);
#pragma unroll
        for (int nt = 0; nt < 4; ++nt)
#pragma unroll
          for (int j = 0; j < 4; ++j)
            dst[(((lane >> 4) << 2) + j) * 132 + (nt << 4)] = acc[nt][j];
      }
    }
    __syncthreads();  // sync1: lz partials + lxz[t&1] visible

    float ho = 0.0f;
    if (tid < 256) {  // ---- gates: 1 cell; h stored DIRECTLY (coalesced) ----
      f32x4 z0 = *(const f32x4*)(lz + 0 * 1056 + rl * 132 + (ul << 2));
      f32x4 z1 = *(const f32x4*)(lz + 1 * 1056 + rl * 132 + (ul << 2));
      f32x4 z2 = *(const f32x4*)(lz + 2 * 1056 + rl * 132 + (ul << 2));
      f32x4 z3 = *(const f32x4*)(lz + 3 * 1056 + rl * 132 + (ul << 2));
      f32x4 z = z0 + z1 + z2 + z3;
      f32x4 xv = *(const f32x4*)(lxz + (t & 1) * 1056 + rl * 132 + (ul << 2));
      float zi = ak * xv[0] + bias_c[0] + ar * z[0];
      float zf = ak * xv[1] + bias_c[1] + ar * z[1];
      float zg = ak * xv[2] + bias_c[2] + ar * z[2];
      float zo = ak * xv[3] + bias_c[3] + ar * z[3];
      float ig = sigm(zi), fg = sigm(zf), gg = tanhx(zg), og = sigm(zo);
      float cn = fg * cst + ig * gg;
      cst = cn;
      ho = og * tanhx(cn);
      st_cc2(hst + (((t + 1) & 1) << 16), bf16b(ho));
      asm volatile("s_waitcnt vmcnt(0)" ::: "memory");  // h acked before bar
    }
    __syncthreads();  // sync2: all h stores of this WG are globally visible

    // ---- arrive: one flag store on the (group,quarter) line ----
    if (wave == 4 && lane == 0) stflag(myflag, t + 1);

    // ---- hidden window: out store + x-projection of t+1 ----
    if (tid < 256) outp[(size_t)t << 10] = ho;
    if (t != T_N - 1) xproj(t + 1, (t + 1) & 1);
    // no end barrier: next iteration's per-wave wait is the sync
  }
}

// ---------------------------------------------------------------------------
extern "C" void kernel_launch(void* const* d_in, const int* in_sizes, int n_in,
                              void* d_out, int out_size, void* d_ws, size_t ws_size,
                              hipStream_t stream) {
  const float* x = (const float*)d_in[0];
  const float* wk = (const float*)d_in[1];
  const float* wr = (const float*)d_in[2];
  const float* bs = (const float*)d_in[3];
  float* out = (float*)d_out;
  char* ws = (char*)d_ws;

  float* alphas = (float*)(ws + 0);
  double* pk = (double*)(ws + 1024);   // 256 doubles: 1024..3072
  int* flags = (int*)(ws + 4096);      // 8 groups x 4 quarters x 128B = 4KB
  double* pr = (double*)(ws + 8192);   // 256 doubles: 8192..10240
  __hip_bfloat16* wtk = (__hip_bfloat16*)(ws + 16384);               // 4 MB
  __hip_bfloat16* wtr = (__hip_bfloat16*)(ws + 16384 + (4 << 20));   // 8 MB
  __hip_bfloat16* hbuf = (__hip_bfloat16*)(ws + 16384 + (12 << 20)); // 256 KB

  absum_kernel<<<256, 256, 0, stream>>>(wk, 512 * 4096, pk);
  absum_kernel<<<256, 256, 0, stream>>>(wr, 1024 * 4096, pr);
  alpha_finalize<<<1, 256, 0, stream>>>(pk, pr, alphas);
  quant_kernel<<<(4096 * 512) / 256, 256, 0, stream>>>(wk, 9, alphas, 0, wtk,
                                                       4096 * 512);
  quant_kernel<<<(4096 * 1024) / 256, 256, 0, stream>>>(wr, 10, alphas, 1, wtr,
                                                        4096 * 1024);
  (void)hipMemsetAsync(flags, 0, 4096);

  const int smem = 131072 + 16896 + 8448 + 64;  // 156480 B -> 1 WG/CU
  (void)hipFuncSetAttribute((const void*)lstm_persist,
                            hipFuncAttributeMaxDynamicSharedMemorySize, smem);
  void* args[] = {(void*)&bs,  (void*)&alphas, (void*)&x,   (void*)&wtk,
                  (void*)&wtr, (void*)&hbuf,   (void*)&out, (void*)&flags};
  (void)hipLaunchCooperativeKernel((void*)lstm_persist, dim3(NWG), dim3(WGT),
                                   args, smem, stream);
}

// Round 6
// 10668.344 us; speedup vs baseline: 1.0448x; 1.0448x over previous
//
#include <hip/hip_runtime.h>
#include <hip/hip_bf16.h>

// ---------------------------------------------------------------------------
// TernaryLSTM R20 = R19 with the h-store ACK pulled off the gates path.
//   Theory: per-step chain = serial device-scope IC hops; R19 paid one full
//   hop inside gates (256 threads each st_cc2 + vmcnt(0) before sync2).
//   R20: gates write h to a 512B LDS slab only; after sync2, WAVE 4 alone
//   blob-stores the whole slice (64x dwordx2 sc0sc1) + vmcnt(0) + flag,
//   overlapping the ack with the other waves' xproj/poll. Poll loop gains
//   s_sleep(2) backoff (cut standing IC poll pressure).
//   Everything else identical to R19: per-wave quarter waits (waves 0-3
//   poll 8 flags each -> LDS epoch; waves 4-7 take epoch), flags on one
//   128B line per (group,quarter), Wr in VGPRs (8 waves x 32 bf16x8),
//   Wk in LDS (128KB XOR-swizzled), xproj(t+1) in the hidden window,
//   all cross-WG ops sc0 sc1 (device/IC scope — R12/R15/R18/R19-proven).
// ---------------------------------------------------------------------------

typedef __attribute__((ext_vector_type(8))) __bf16 bf16x8;
typedef __attribute__((ext_vector_type(4))) float f32x4;
typedef __attribute__((ext_vector_type(2))) unsigned int u32x2;

#define NWG 256
#define WGT 512
#define T_N 1024

// ---------------- alpha reductions -----------------------------------------
__global__ void absum_kernel(const float* __restrict__ w, int n,
                             double* __restrict__ partial) {
  __shared__ double sd[256];
  double s = 0.0;
  for (int i = blockIdx.x * 256 + threadIdx.x; i < n; i += 256 * 256)
    s += fabs((double)w[i]);
  sd[threadIdx.x] = s;
  __syncthreads();
  for (int k = 128; k > 0; k >>= 1) {
    if (threadIdx.x < k) sd[threadIdx.x] += sd[threadIdx.x + k];
    __syncthreads();
  }
  if (threadIdx.x == 0) partial[blockIdx.x] = sd[0];
}

__global__ void alpha_finalize(const double* __restrict__ pk,
                               const double* __restrict__ pr,
                               float* __restrict__ alphas) {
  __shared__ double sd[256];
  int t = threadIdx.x;
  sd[t] = pk[t];
  __syncthreads();
  for (int s = 128; s > 0; s >>= 1) {
    if (t < s) sd[t] += sd[t + s];
    __syncthreads();
  }
  if (t == 0) alphas[0] = (float)(sd[0] / (512.0 * 4096.0));
  __syncthreads();
  sd[t] = pr[t];
  __syncthreads();
  for (int s = 128; s > 0; s >>= 1) {
    if (t < s) sd[t] += sd[t + s];
    __syncthreads();
  }
  if (t == 0) alphas[1] = (float)(sd[0] / (1024.0 * 4096.0));
}

// ------ quantize + transpose to UNIT-MAJOR cols: wt[u*4+g][k] --------------
__global__ void quant_kernel(const float* __restrict__ w, int kbits,
                             const float* __restrict__ alphas, int ai,
                             __hip_bfloat16* __restrict__ wt, int total) {
  int idx = blockIdx.x * 256 + threadIdx.x;
  if (idx >= total) return;
  float thr = 0.7f * alphas[ai];
  int K = 1 << kbits;
  int c = idx >> kbits;  // unit-major col: unit = c>>2, gate = c&3
  int k = idx & (K - 1);
  float v = w[k * 4096 + (c & 3) * 1024 + (c >> 2)];
  float q = (fabsf(v) < thr) ? 0.0f : ((v > 0.0f) ? 1.0f : ((v < 0.0f) ? -1.0f : 0.0f));
  wt[idx] = __float2bfloat16(q);  // exact {-1,0,+1}
}

// ---------------- helpers ---------------------------------------------------
__device__ __forceinline__ bf16x8 cvt2(f32x4 a, f32x4 b) {
  bf16x8 r;
  r[0] = (__bf16)a[0]; r[1] = (__bf16)a[1];
  r[2] = (__bf16)a[2]; r[3] = (__bf16)a[3];
  r[4] = (__bf16)b[0]; r[5] = (__bf16)b[1];
  r[6] = (__bf16)b[2]; r[7] = (__bf16)b[3];
  return r;
}
// Device-scope (IC) ops — R12/R15/R18/R19-proven protocol.
__device__ __forceinline__ void ld16cc(bf16x8* d, const __hip_bfloat16* p) {
  asm volatile("global_load_dwordx4 %0, %1, off sc0 sc1"
               : "=v"(*d) : "v"(p) : "memory");
}
__device__ __forceinline__ void st8cc(__hip_bfloat16* p, u32x2 v) {
  asm volatile("global_store_dwordx2 %0, %1, off sc0 sc1" ::"v"(p), "v"(v)
               : "memory");
}
__device__ __forceinline__ void stflag(int* p, int v) {
  asm volatile("global_store_dword %0, %1, off sc0 sc1" ::"v"(p), "v"(v)
               : "memory");
}
__device__ __forceinline__ int ldflag(const int* p) {
  int v;
  asm volatile("global_load_dword %0, %1, off sc0 sc1\n\ts_waitcnt vmcnt(0)"
               : "=v"(v) : "v"(p) : "memory");
  return v;
}
__device__ __forceinline__ unsigned bf16b(float f) {
  return (unsigned)__builtin_bit_cast(unsigned short, __float2bfloat16(f));
}
__device__ __forceinline__ float sigm(float z) { return 1.0f / (1.0f + __expf(-z)); }
__device__ __forceinline__ float tanhx(float z) {
  float e = __expf(-2.0f * fabsf(z));
  return __builtin_copysignf((1.0f - e) / (1.0f + e), z);
}

// ---------------- persistent LSTM kernel -----------------------------------
// flags layout: flags[(g*4 + quarter)*32 + slot], slot = u&7 (one 128B line
// per (group, quarter); 8 writers, 32 pollers per line).
__global__ void __launch_bounds__(WGT, 2)
lstm_persist(const float* __restrict__ bias4, const float* __restrict__ alphas,
             const float* __restrict__ x,             // [B][T][I] f32
             const __hip_bfloat16* __restrict__ wtk,  // [4096][512]  unit-major
             const __hip_bfloat16* __restrict__ wtr,  // [4096][1024] unit-major
             __hip_bfloat16* __restrict__ hbuf,       // [2][8][8][1024] bf16
             float* __restrict__ out,                 // [B][T][U] f32
             int* __restrict__ flags) {
  extern __shared__ char lds[];
  char* lwtk = lds;                     // 128 cols x 1024B swizzled = 131072
  float* lz = (float*)(lds + 131072);   // 4 slabs x [8][132] f32 = 16896
  float* lxz = (float*)(lds + 147968);  // 2 bufs  x [8][132] f32 = 8448
  unsigned short* lhs = (unsigned short*)(lds + 156416);  // 256 ushort = 512
  int* lmeta = (int*)(lds + 156928);    // [0..3] per-quarter epoch

  const int tid = threadIdx.x;
  const int wg = blockIdx.x;
  const int lane = tid & 63;
  const int wave = tid >> 6;
  const int r16 = lane & 15;
  const int kb8 = (lane >> 4) << 3;  // k-chunk 0,8,16,24

  const int g = wg >> 5;   // software group 0..7 (8 batch rows each)
  const int u = wg & 31;   // unit-block 0..31: units [32u, 32u+32)
  const int rb0 = g << 3;  // group's first batch row

  if (tid < 4) lmeta[tid] = 0;

  // my flag slot (written by wave4 lane0): line (g, quarter u>>3), slot u&7
  int* myflag = flags + ((g << 2) + (u >> 3)) * 32 + (u & 7);
  // poll line for wave<4: quarter = wave
  const int* pollp = flags + ((g << 2) + (wave & 3)) * 32 + (lane & 7);

  // ---- stage Wk slice into LDS: local cols [0,128) = global [128u,+128) ---
  for (int it = tid; it < 8192; it += WGT) {
    int c = it >> 6, kk = (it & 63) << 3;
    bf16x8 v = *(const bf16x8*)(wtk + (size_t)(u * 128 + c) * 512 + kk);
    *(bf16x8*)(lwtk + (c << 10) + ((kk << 1) ^ ((c & 7) << 4))) = v;
  }

  // ---- Wr slice into VGPRs: wave w -> k-slice [(w&3)*256,+256),
  //      col half (w>>2)*64: 8 ksteps x 4 ntiles of bf16x8 frags ----
  const int ks0 = (wave & 3) << 8;
  bf16x8 bw[8][4];
  {
    const __hip_bfloat16* wb =
        wtr + (size_t)(u * 128 + ((wave >> 2) << 6) + r16) * 1024 + ks0 + kb8;
#pragma unroll
    for (int ks = 0; ks < 8; ++ks)
#pragma unroll
      for (int nt = 0; nt < 4; ++nt)
        bw[ks][nt] = *(const bf16x8*)(wb + (size_t)nt * 16 * 1024 + (ks << 5));
  }

  const float ak = alphas[0];
  const float ar = alphas[1];

  // gates mapping (threads 0..255): 1 cell = (row rl 0..7, unit-local ul 0..31)
  const int rl = tid >> 5;
  const int ul = tid & 31;
  float bias_c[4];
#pragma unroll
  for (int gg = 0; gg < 4; ++gg)
    bias_c[gg] = bias4[gg * 1024 + u * 32 + ul];
  float cst = 0.0f;
  float* outp = out + ((size_t)(rb0 + rl) << 20) + u * 32 + ul;

  // x-projection of step tt into lxz[par]: wave w does n-tile w (16 cols).
  auto xproj = [&](int tt, int par) {
    const float* xr =
        x + ((size_t)(rb0 + (r16 & 7)) << 19) + ((size_t)tt << 9) + kb8;
    const int cloc = (wave << 4) + r16;
    const char* bbase = lwtk + (cloc << 10);
    const int bxor = (cloc & 7) << 4;
    f32x4 a = {0.f, 0.f, 0.f, 0.f};
#pragma unroll
    for (int kw = 0; kw < 16; ++kw) {
      bf16x8 af = cvt2(*(const f32x4*)(xr + kw * 32),
                       *(const f32x4*)(xr + kw * 32 + 4));
      bf16x8 bf = *(const bf16x8*)(bbase + ((((kw << 5) + kb8) << 1) ^ bxor));
      a = __builtin_amdgcn_mfma_f32_16x16x32_bf16(af, bf, a, 0, 0, 0);
    }
    if (lane < 32) {
      float* dst = lxz + par * 1056 + (wave << 4) + (lane & 15);
#pragma unroll
      for (int j = 0; j < 4; ++j)
        dst[(((lane >> 4) << 2) + j) * 132] = a[j];
    }
  };

  __syncthreads();  // staging + lmeta visible
  xproj(0, 0);      // prologue: t=0 x-projection into lxz[0]

  // ---- main loop ----
  for (int t = 0; t < T_N; ++t) {
    // ---- rec: all 8 waves, per-wave producer wait + k-slice MFMA ----
    {
      f32x4 acc[4];
#pragma unroll
      for (int nt = 0; nt < 4; ++nt) acc[nt] = (f32x4){0.f, 0.f, 0.f, 0.f};
      if (t > 0) {
        // per-wave wait: quarter (w&3) needs its 8 producers at >= t.
        if (wave < 4) {
          for (;;) {
            int v = (lane < 8) ? ldflag(pollp) : 0x7fffffff;
            if (__all(v >= t)) break;
            __builtin_amdgcn_s_sleep(2);  // backoff: cut IC poll pressure
          }
          if (lane == 0)
            __hip_atomic_store(&lmeta[wave], t, __ATOMIC_RELEASE,
                               __HIP_MEMORY_SCOPE_WORKGROUP);
        } else {
          while (__hip_atomic_load(&lmeta[wave - 4], __ATOMIC_ACQUIRE,
                                   __HIP_MEMORY_SCOPE_WORKGROUP) < t) {}
        }
        bf16x8 fr[8];
        if (r16 < 8) {  // A rows 8..15 are zero padding
          const __hip_bfloat16* hrow =
              hbuf + ((t & 1) << 16) + (g << 13) + (r16 << 10) + ks0 + kb8;
#pragma unroll
          for (int ks = 0; ks < 8; ++ks) ld16cc(&fr[ks], hrow + (ks << 5));
        } else {
#pragma unroll
          for (int ks = 0; ks < 8; ++ks)
#pragma unroll
            for (int j = 0; j < 8; ++j) fr[ks][j] = (__bf16)0.0f;
        }
        asm volatile("s_waitcnt vmcnt(0)" ::: "memory");
        __builtin_amdgcn_sched_barrier(0);
#pragma unroll
        for (int ks = 0; ks < 8; ++ks)
#pragma unroll
          for (int nt = 0; nt < 4; ++nt)
            acc[nt] = __builtin_amdgcn_mfma_f32_16x16x32_bf16(
                fr[ks], bw[ks][nt], acc[nt], 0, 0, 0);
      }
      if (lane < 32) {  // store C rows 0..7 only
        float* dst = lz + (wave & 3) * 1056 + ((wave >> 2) << 6) + (lane & 15);
#pragma unroll
        for (int nt = 0; nt < 4; ++nt)
#pragma unroll
          for (int j = 0; j < 4; ++j)
            dst[(((lane >> 4) << 2) + j) * 132 + (nt << 4)] = acc[nt][j];
      }
    }
    __syncthreads();  // sync1: lz partials + lxz[t&1] visible

    float ho = 0.0f;
    if (tid < 256) {  // ---- gates: 1 cell; h -> LDS slab (NO global ack) ----
      f32x4 z0 = *(const f32x4*)(lz + 0 * 1056 + rl * 132 + (ul << 2));
      f32x4 z1 = *(const f32x4*)(lz + 1 * 1056 + rl * 132 + (ul << 2));
      f32x4 z2 = *(const f32x4*)(lz + 2 * 1056 + rl * 132 + (ul << 2));
      f32x4 z3 = *(const f32x4*)(lz + 3 * 1056 + rl * 132 + (ul << 2));
      f32x4 z = z0 + z1 + z2 + z3;
      f32x4 xv = *(const f32x4*)(lxz + (t & 1) * 1056 + rl * 132 + (ul << 2));
      float zi = ak * xv[0] + bias_c[0] + ar * z[0];
      float zf = ak * xv[1] + bias_c[1] + ar * z[1];
      float zg = ak * xv[2] + bias_c[2] + ar * z[2];
      float zo = ak * xv[3] + bias_c[3] + ar * z[3];
      float ig = sigm(zi), fg = sigm(zf), gg = tanhx(zg), og = sigm(zo);
      float cn = fg * cst + ig * gg;
      cst = cn;
      ho = og * tanhx(cn);
      lhs[tid] = (unsigned short)bf16b(ho);
      outp[(size_t)t << 10] = ho;  // fire-and-forget cached store
    }
    __syncthreads();  // sync2: lhs visible to wave4

    // ---- wave4 alone: blob h-store + ack + flag (overlaps others' xproj) --
    if (wave == 4) {
      u32x2 dv = *(const u32x2*)(lhs + (lane << 2));
      __hip_bfloat16* hb = hbuf + (((t + 1) & 1) << 16) + (g << 13) +
                           ((lane >> 3) << 10) + u * 32 + ((lane & 7) << 2);
      st8cc(hb, dv);
      asm volatile("s_waitcnt vmcnt(0)" ::: "memory");
      if (lane == 0) stflag(myflag, t + 1);
    }

    // ---- hidden window: x-projection of t+1 (all waves) ----
    if (t != T_N - 1) xproj(t + 1, (t + 1) & 1);
    // no end barrier: next iteration's per-wave wait is the sync
  }
}

// ---------------------------------------------------------------------------
extern "C" void kernel_launch(void* const* d_in, const int* in_sizes, int n_in,
                              void* d_out, int out_size, void* d_ws, size_t ws_size,
                              hipStream_t stream) {
  const float* x = (const float*)d_in[0];
  const float* wk = (const float*)d_in[1];
  const float* wr = (const float*)d_in[2];
  const float* bs = (const float*)d_in[3];
  float* out = (float*)d_out;
  char* ws = (char*)d_ws;

  float* alphas = (float*)(ws + 0);
  double* pk = (double*)(ws + 1024);   // 256 doubles: 1024..3072
  int* flags = (int*)(ws + 4096);      // 8 groups x 4 quarters x 128B = 4KB
  double* pr = (double*)(ws + 8192);   // 256 doubles: 8192..10240
  __hip_bfloat16* wtk = (__hip_bfloat16*)(ws + 16384);               // 4 MB
  __hip_bfloat16* wtr = (__hip_bfloat16*)(ws + 16384 + (4 << 20));   // 8 MB
  __hip_bfloat16* hbuf = (__hip_bfloat16*)(ws + 16384 + (12 << 20)); // 256 KB

  absum_kernel<<<256, 256, 0, stream>>>(wk, 512 * 4096, pk);
  absum_kernel<<<256, 256, 0, stream>>>(wr, 1024 * 4096, pr);
  alpha_finalize<<<1, 256, 0, stream>>>(pk, pr, alphas);
  quant_kernel<<<(4096 * 512) / 256, 256, 0, stream>>>(wk, 9, alphas, 0, wtk,
                                                       4096 * 512);
  quant_kernel<<<(4096 * 1024) / 256, 256, 0, stream>>>(wr, 10, alphas, 1, wtr,
                                                        4096 * 1024);
  (void)hipMemsetAsync(flags, 0, 4096);

  const int smem = 131072 + 16896 + 8448 + 512 + 64;  // 156992 B -> 1 WG/CU
  (void)hipFuncSetAttribute((const void*)lstm_persist,
                            hipFuncAttributeMaxDynamicSharedMemorySize, smem);
  void* args[] = {(void*)&bs,  (void*)&alphas, (void*)&x,   (void*)&wtk,
                  (void*)&wtr, (void*)&hbuf,   (void*)&out, (void*)&flags};
  (void)hipLaunchCooperativeKernel((void*)lstm_persist, dim3(NWG), dim3(WGT),
                                   args, smem, stream);
}